// Round 19
// baseline (14232.736 us; speedup 1.0000x reference)
//
#include <hip/hip_runtime.h>
#include <math.h>

#define BDIM 512
#define BR   32
#define D    128
#define SPD  130      // state LDS row stride (doubles)
#define WSP  130      // W' LDS row stride (doubles)
#define TT   32
#define NB   8
#define NL   3

typedef double v4d __attribute__((ext_vector_type(4)));

__device__ __forceinline__ double c19_act_d(double x) {
    const double PI_D = 3.14159265358979323846;
    const double L6   = 6.0 * PI_D;
    double scaled = x * (1.0 / PI_D);
    double n = floor(scaled);
    double t = scaled - n;
    double h = t * (1.0 - t);
    double halfn = n * 0.5;
    double fr = halfn - floor(halfn);
    double sgn = (fr < 0.25) ? 1.0 : -1.0;
    double core = PI_D * (sgn * h + 4.0 * h * h);
    double r = core;
    r = (x <= -L6) ? (x + L6) : r;
    r = (x >=  L6) ? (x - L6) : r;
    return r;
}

// prep: W'[ly][k][c] = g[ly][k] * W[ly][k][c]  (f64, exact fold) into d_ws
__global__ void miniphi_prep(const float* __restrict__ Ws, const float* __restrict__ gs,
                             double* __restrict__ wp) {
    int idx = blockIdx.x * 256 + threadIdx.x;   // 0 .. 49151
    wp[idx] = (double)gs[idx >> 7] * (double)Ws[idx];
}

__global__ __launch_bounds__(BDIM) void miniphi_kernel(
    const float* __restrict__ x,  const float* __restrict__ Wi, const float* __restrict__ bi,
    const float* __restrict__ Wo, const float* __restrict__ bo,
    const float* __restrict__ g_state, const float* __restrict__ b_state,
    const float* __restrict__ Ws, const float* __restrict__ bs,
    const float* __restrict__ gs, const float* __restrict__ betas,
    const double* __restrict__ wp,   // f64 g-folded W' in ws (or nullptr)
    float* __restrict__ out)
{
    // LDS budget 73,220 B -> 2 blocks/CU (16 waves/CU) with 512-thread blocks
    __shared__ double sState[BR][SPD];     // 33280 B
    __shared__ double sWq[2][16][WSP];     // 33280 B  W' eighth double-buffer
    __shared__ double sGW[NL][D];          //  3072 B  (g @ W)[c]
    __shared__ double sBWbs[NL][D];        //  3072 B  (beta @ W)[c] + bs[c]
    __shared__ double sRstd[BR], sMu2[BR]; //   512 B
    __shared__ int    sFlag;               //     4 B

    const int tid  = threadIdx.x;
    const int lane = tid & 63;
    const int wv   = tid >> 6;             // wave 0..7

    for (int i = tid; i < BR * D; i += BDIM) sState[i >> 7][i & 127] = 0.0;
    if (tid == 0) sFlag = 1;
    if (tid < NL * D) {
        int ly = tid >> 7, c = tid & 127;
        const float* wl = Ws + (size_t)ly * D * D;
        double gw = 0.0, bw = 0.0;
        for (int k = 0; k < D; ++k) {
            double w = (double)wl[k * D + c];
            gw = fma((double)gs[ly * D + k], w, gw);
            bw = fma((double)betas[ly * D + k], w, bw);
        }
        sGW[ly][c] = gw;
        sBWbs[ly][c] = bw + (double)bs[ly * D + c];
    }
    __syncthreads();

    // ---- MFMA self-calibration probes (every wave; maps kept in registers) ----
    const int lm = lane & 15, lk = lane >> 4;
    int pr[4], pc[4];
    {
        v4d z = {0.0, 0.0, 0.0, 0.0};
        v4d p1 = __builtin_amdgcn_mfma_f64_16x16x4f64((double)lm, 1.0, z, 0, 0, 0);
        v4d p2 = __builtin_amdgcn_mfma_f64_16x16x4f64(1.0, (double)lm, z, 0, 0, 0);
        double pk = (double)(1 << lk);
        v4d p3 = __builtin_amdgcn_mfma_f64_16x16x4f64(pk, pk, z, 0, 0, 0);
        v4d p4 = __builtin_amdgcn_mfma_f64_16x16x4f64(1.0 + 0x1p-30, 1.0, z, 0, 0, 0);
        double pa5 = (lk == 0) ? 1.0 : 0x1p-52;
        v4d p5 = __builtin_amdgcn_mfma_f64_16x16x4f64(pa5, 1.0, z, 0, 0, 0);
        bool ok = true;
        #pragma unroll
        for (int i = 0; i < 4; ++i) {
            double v = p1[i]; int r = (int)(v * 0.25 + 0.5);
            ok = ok && (v == 4.0 * (double)r) && (r >= 0) && (r < 16);
            pr[i] = r;
            double w = p2[i]; int c2 = (int)(w * 0.25 + 0.5);
            ok = ok && (w == 4.0 * (double)c2) && (c2 >= 0) && (c2 < 16);
            pc[i] = c2;
            ok = ok && (p3[i] == 85.0);
            ok = ok && (p4[i] == 4.0 + 0x1p-28);
            ok = ok && (p5[i] == 1.0 + 3.0 * 0x1p-52);
        }
        unsigned long long bal = __ballot(ok ? 1 : 0);
        if (lane == 0 && bal != 0xFFFFFFFFFFFFFFFFull) atomicAnd(&sFlag, 0);
    }
    __syncthreads();
    const int useMfma = sFlag;

    const int rLN = tid >> 4;              // 0..31 : LN row (wave w -> rows 4w..4w+3)
    const int sL  = tid & 15;              // lane owns cols {sL + 16*j, j=0..7}
    const int c0  = wv * 16;               // MFMA col tile
    const int r0v = wv * 4;                // fallback rows (4/wave)
    const size_t rowg = (size_t)blockIdx.x * BR;

    // stage one 16-k-row eighth of W' into sWq[QB]
    #define STAGE_E(LY, E, QB)                                                      \
      { if (wp) {                                                                   \
          const double* src = wp + (((size_t)(LY) * D + (E) * 16) * D);             \
          _Pragma("unroll")                                                         \
          for (int i_ = 0; i_ < 2; ++i_) {                                          \
              int kr_ = wv * 2 + i_;                                                \
              const double* g_ = src + (size_t)kr_ * D + lane * 2;                  \
              __builtin_amdgcn_global_load_lds(                                     \
                  (const __attribute__((address_space(1))) void*)g_,                \
                  (__attribute__((address_space(3))) void*)&sWq[QB][kr_][0],        \
                  16, 0, 0);                                                        \
          }                                                                         \
        } else {                                                                    \
          const float* src = Ws + (((size_t)(LY) * D + (E) * 16) * D);              \
          const float* gl  = gs + (LY) * D + (E) * 16;                              \
          _Pragma("unroll")                                                         \
          for (int i_ = 0; i_ < 2; ++i_) {                                          \
              int kr_ = wv * 2 + i_;                                                \
              float2 w_ = *(const float2*)(src + (size_t)kr_ * D + lane * 2);       \
              double g_ = (double)gl[kr_];                                          \
              double2 o_; o_.x = g_ * (double)w_.x; o_.y = g_ * (double)w_.y;       \
              *(double2*)&sWq[QB][kr_][lane * 2] = o_;                              \
          }                                                                         \
        } }

    // MFMA eighth: reads sWq[QB], state k-range [KB, KB+16)
    #define GEMM_E(QB, KB)                                                          \
      if (useMfma) {                                                                \
          _Pragma("unroll")                                                         \
          for (int k0 = 0; k0 < 16; k0 += 4) {                                      \
              double b  = sWq[QB][k0 + lk][c0 + lm];                                \
              double a0 = sState[lm     ][(KB) + k0 + lk];                          \
              double a1 = sState[lm + 16][(KB) + k0 + lk];                          \
              acc0 = __builtin_amdgcn_mfma_f64_16x16x4f64(a0, b, acc0, 0, 0, 0);    \
              acc1 = __builtin_amdgcn_mfma_f64_16x16x4f64(a1, b, acc1, 0, 0, 0);    \
          }                                                                         \
      } else {                                                                      \
          _Pragma("unroll")                                                         \
          for (int kk = 0; kk < 16; kk += 2) {                                      \
              int kg = (KB) + kk;                                                   \
              double b00 = sWq[QB][kk][lane],     b01 = sWq[QB][kk][lane + 64];     \
              double b10 = sWq[QB][kk + 1][lane], b11 = sWq[QB][kk + 1][lane + 64]; \
              _Pragma("unroll")                                                     \
              for (int r = 0; r < 4; ++r) {                                         \
                  double2 a = *(const double2*)&sState[r0v + r][kg];                \
                  accv[r][0] = fma(a.y, b10, fma(a.x, b00, accv[r][0]));            \
                  accv[r][1] = fma(a.y, b11, fma(a.x, b01, accv[r][1]));            \
              }                                                                     \
          }                                                                         \
      }

    STAGE_E(0, 0, 0)   // t=0 prologue; drained at the post-step1 barrier

    for (int t = 0; t < TT; ++t) {
        // ---------- step 1 (wave-private rows); Wi/bi/g_state/b_state from L1 ----------
        {
            const float* xp = x + (rowg + (size_t)rLN) * (TT * NB) + (size_t)t * NB;
            float4 xa = *(const float4*)(xp);
            float4 xb = *(const float4*)(xp + 4);
            double xv[8] = {(double)xa.x, (double)xa.y, (double)xa.z, (double)xa.w,
                            (double)xb.x, (double)xb.y, (double)xb.z, (double)xb.w};
            double v[8];
            #pragma unroll
            for (int j = 0; j < 8; ++j) v[j] = sState[rLN][sL + 16 * j];
            double sum = 0.0;
            #pragma unroll
            for (int j = 0; j < 8; ++j) sum += v[j];
            sum += __shfl_xor(sum, 1); sum += __shfl_xor(sum, 2);
            sum += __shfl_xor(sum, 4); sum += __shfl_xor(sum, 8);
            double mu = sum * (1.0 / 128.0);
            double sq = 0.0;
            #pragma unroll
            for (int j = 0; j < 8; ++j) { double dd = v[j] - mu; sq += dd * dd; }
            sq += __shfl_xor(sq, 1); sq += __shfl_xor(sq, 2);
            sq += __shfl_xor(sq, 4); sq += __shfl_xor(sq, 8);
            double rstd = 1.0 / sqrt(sq * (1.0 / 128.0) + 1e-5);
            #pragma unroll
            for (int j = 0; j < 8; ++j) {
                int c = sL + 16 * j;
                double inp = (double)bi[c];
                #pragma unroll
                for (int k = 0; k < 8; ++k)
                    inp = fma(xv[k], (double)Wi[k * D + c], inp);
                double ln = (v[j] - mu) * rstd * (double)g_state[c] + (double)b_state[c];
                sState[rLN][c] = 0.618 * ln + 0.382 * inp;
            }
        }
        __syncthreads();   // state ready; layer-0 e0 staged & drained

        // ---------- step 2: 3 residual layers; LN fused into e0's MFMA shadow ----------
        for (int ly = 0; ly < NL; ++ly) {
            v4d acc0 = {0,0,0,0}, acc1 = {0,0,0,0};
            double accv[4][2];
            #pragma unroll
            for (int r = 0; r < 4; ++r) { accv[r][0] = 0.0; accv[r][1] = 0.0; }

            // e0 region: stage e1 | MFMA e0 | LN (streamed)
            STAGE_E(ly, 1, 1)
            GEMM_E(0, 0)
            {
                double sum = 0.0;
                #pragma unroll
                for (int j = 0; j < 8; ++j) sum += sState[rLN][sL + 16 * j];
                sum += __shfl_xor(sum, 1); sum += __shfl_xor(sum, 2);
                sum += __shfl_xor(sum, 4); sum += __shfl_xor(sum, 8);
                double mu = sum * (1.0 / 128.0);
                double sq = 0.0;
                #pragma unroll
                for (int j = 0; j < 8; ++j) { double dd = sState[rLN][sL + 16 * j] - mu; sq += dd * dd; }
                sq += __shfl_xor(sq, 1); sq += __shfl_xor(sq, 2);
                sq += __shfl_xor(sq, 4); sq += __shfl_xor(sq, 8);
                double rstd = 1.0 / sqrt(sq * (1.0 / 128.0) + 1e-5);
                if (sL == 0) { sRstd[rLN] = rstd; sMu2[rLN] = mu * rstd; }
            }
            __syncthreads();

            STAGE_E(ly, 2, 0) GEMM_E(1, 16)  __syncthreads();
            STAGE_E(ly, 3, 1) GEMM_E(0, 32)  __syncthreads();
            STAGE_E(ly, 4, 0) GEMM_E(1, 48)  __syncthreads();
            STAGE_E(ly, 5, 1) GEMM_E(0, 64)  __syncthreads();
            STAGE_E(ly, 6, 0) GEMM_E(1, 80)  __syncthreads();
            STAGE_E(ly, 7, 1) GEMM_E(0, 96)  __syncthreads();
            if (ly + 1 < NL) { STAGE_E(ly + 1, 0, 0) } else { STAGE_E(0, 0, 0) }
            GEMM_E(1, 112)
            __syncthreads();

            // epilogue
            if (useMfma) {
                #pragma unroll
                for (int i = 0; i < 4; ++i) {
                    int col = c0 + pc[i];
                    double gwc = sGW[ly][col], bwc = sBWbs[ly][col];
                    int R0 = pr[i];
                    double y0 = fma(sRstd[R0],      acc0[i], fma(-sMu2[R0],      gwc, bwc));
                    double y1 = fma(sRstd[R0 + 16], acc1[i], fma(-sMu2[R0 + 16], gwc, bwc));
                    sState[R0][col]      += c19_act_d(y0);
                    sState[R0 + 16][col] += c19_act_d(y1);
                }
            } else {
                double gwc0 = sGW[ly][lane],   gwc1 = sGW[ly][lane + 64];
                double bwc0 = sBWbs[ly][lane], bwc1 = sBWbs[ly][lane + 64];
                #pragma unroll
                for (int r = 0; r < 4; ++r) {
                    int R = r0v + r;
                    double rs = sRstd[R], m2 = sMu2[R];
                    double y0 = fma(rs, accv[r][0], fma(-m2, gwc0, bwc0));
                    double y1 = fma(rs, accv[r][1], fma(-m2, gwc1, bwc1));
                    sState[R][lane]      += c19_act_d(y0);
                    sState[R][lane + 64] += c19_act_d(y1);
                }
            }
            __syncthreads();   // state final for next LN/GEMM/step3
        }

        // ---------- step 3: out = state @ Wo + bo (own rows); Wo from L1 ----------
        {
            double accj[8];
            #pragma unroll
            for (int j = 0; j < 8; ++j) accj[j] = 0.0;
            #pragma unroll
            for (int u = 0; u < 8; ++u) {
                int k = sL + 16 * u;
                double s = sState[rLN][k];
                float4 w0 = *(const float4*)&Wo[k * NB];
                float4 w1 = *(const float4*)&Wo[k * NB + 4];
                accj[0] = fma(s, (double)w0.x, accj[0]);
                accj[1] = fma(s, (double)w0.y, accj[1]);
                accj[2] = fma(s, (double)w0.z, accj[2]);
                accj[3] = fma(s, (double)w0.w, accj[3]);
                accj[4] = fma(s, (double)w1.x, accj[4]);
                accj[5] = fma(s, (double)w1.y, accj[5]);
                accj[6] = fma(s, (double)w1.z, accj[6]);
                accj[7] = fma(s, (double)w1.w, accj[7]);
            }
            #pragma unroll
            for (int j = 0; j < 8; ++j) {
                accj[j] += __shfl_xor(accj[j], 1);
                accj[j] += __shfl_xor(accj[j], 2);
                accj[j] += __shfl_xor(accj[j], 4);
                accj[j] += __shfl_xor(accj[j], 8);
            }
            double o = accj[0];
            #pragma unroll
            for (int j = 1; j < 8; ++j) o = (sL == j) ? accj[j] : o;
            if (sL < NB)
                out[((rowg + (size_t)rLN) * TT + (size_t)t) * NB + sL] =
                    (float)(o + (double)bo[sL]);
        }
    }
    #undef GEMM_E
    #undef STAGE_E
}

extern "C" void kernel_launch(void* const* d_in, const int* in_sizes, int n_in,
                              void* d_out, int out_size, void* d_ws, size_t ws_size,
                              hipStream_t stream) {
    const float* x       = (const float*)d_in[0];
    const float* Wi      = (const float*)d_in[1];
    const float* bi      = (const float*)d_in[2];
    const float* Wo      = (const float*)d_in[3];
    const float* bo      = (const float*)d_in[4];
    const float* g_state = (const float*)d_in[5];
    const float* b_state = (const float*)d_in[6];
    const float* Ws      = (const float*)d_in[7];
    const float* bs      = (const float*)d_in[8];
    const float* gs      = (const float*)d_in[9];
    const float* betas   = (const float*)d_in[10];
    float* out = (float*)d_out;

    const size_t wp_bytes = (size_t)NL * D * D * sizeof(double);   // 393216
    double* wp = (ws_size >= wp_bytes) ? (double*)d_ws : nullptr;
    if (wp) {
        dim3 pgrid(NL * D * D / 256), pblock(256);
        hipLaunchKernelGGL(miniphi_prep, pgrid, pblock, 0, stream, Ws, gs, wp);
    }

    const int B = in_sizes[0] / (TT * NB);   // 65536
    dim3 grid(B / BR), block(BDIM);
    hipLaunchKernelGGL(miniphi_kernel, grid, block, 0, stream,
                       x, Wi, bi, Wo, bo, g_state, b_state, Ws, bs, gs, betas, wp, out);
}

// Round 20
// 5048.542 us; speedup vs baseline: 2.8192x; 2.8192x over previous
//
#include <hip/hip_runtime.h>
#include <math.h>

#define BDIM 1024
#define BR   64
#define D    128
#define SPD  130      // state LDS row stride (doubles)
#define WSP  130      // W' LDS row stride (doubles)
#define SWOP 12       // sWo row stride (floats)
#define TT   32
#define NB   8
#define NL   3

typedef double v4d __attribute__((ext_vector_type(4)));

__device__ __forceinline__ double c19_act_d(double x) {
    const double PI_D = 3.14159265358979323846;
    const double L6   = 6.0 * PI_D;
    double scaled = x * (1.0 / PI_D);
    double n = floor(scaled);
    double t = scaled - n;
    double h = t * (1.0 - t);
    double halfn = n * 0.5;
    double fr = halfn - floor(halfn);
    double sgn = (fr < 0.25) ? 1.0 : -1.0;
    double core = PI_D * (sgn * h + 4.0 * h * h);
    double r = core;
    r = (x <= -L6) ? (x + L6) : r;
    r = (x >=  L6) ? (x - L6) : r;
    return r;
}

// prep: W'[ly][k][c] = g[ly][k] * W[ly][k][c]  (f64, exact fold) into d_ws
__global__ void miniphi_prep(const float* __restrict__ Ws, const float* __restrict__ gs,
                             double* __restrict__ wp) {
    int idx = blockIdx.x * 256 + threadIdx.x;   // 0 .. 49151
    wp[idx] = (double)gs[idx >> 7] * (double)Ws[idx];
}

__global__ __launch_bounds__(BDIM) void miniphi_kernel(
    const float* __restrict__ x,  const float* __restrict__ Wi, const float* __restrict__ bi,
    const float* __restrict__ Wo, const float* __restrict__ bo,
    const float* __restrict__ g_state, const float* __restrict__ b_state,
    const float* __restrict__ Ws, const float* __restrict__ bs,
    const float* __restrict__ gs, const float* __restrict__ betas,
    const double* __restrict__ wp,   // f64 g-folded W' in ws (or nullptr)
    float* __restrict__ out)
{
    __shared__ double sState[BR][SPD];     // 66560 B
    __shared__ double sWq[2][32][WSP];     // 66560 B  W' quarter double-buffer
    __shared__ float  sWi[NB][D];
    __shared__ float  sWo[D][SWOP];
    __shared__ float  sBi[D], sGst[D], sBst[D];
    __shared__ double sGsD[NL][D];         // fallback g (f64)
    __shared__ double sGW[NL][D];          // (g @ W)[c]
    __shared__ double sBWbs[NL][D];        // (beta @ W)[c] + bs[c]
    __shared__ double sRstd[BR], sMu2[BR];
    __shared__ float  sBo[NB];
    __shared__ int    sPR[64][4], sPC[64][4];
    __shared__ int    sFlag;               // ~157.3 KB

    const int tid  = threadIdx.x;
    const int lane = tid & 63;
    const int wv   = tid >> 6;             // wave 0..15

    for (int i = tid; i < NB * D; i += BDIM) sWi[i >> 7][i & 127] = Wi[i];
    for (int i = tid; i < D * NB; i += BDIM) sWo[i >> 3][i & 7] = Wo[i];
    for (int i = tid; i < D; i += BDIM) { sBi[i] = bi[i]; sGst[i] = g_state[i]; sBst[i] = b_state[i]; }
    for (int i = tid; i < NL * D; i += BDIM) sGsD[i >> 7][i & 127] = (double)gs[i];
    if (tid < NB) sBo[tid] = bo[tid];
    for (int i = tid; i < BR * D; i += BDIM) sState[i >> 7][i & 127] = 0.0;
    if (tid < NL * D) {
        int ly = tid >> 7, c = tid & 127;
        const float* wl = Ws + (size_t)ly * D * D;
        double gw = 0.0, bw = 0.0;
        for (int k = 0; k < D; ++k) {
            double w = (double)wl[k * D + c];
            gw = fma((double)gs[ly * D + k], w, gw);
            bw = fma((double)betas[ly * D + k], w, bw);
        }
        sGW[ly][c] = gw;
        sBWbs[ly][c] = bw + (double)bs[ly * D + c];
    }

    // ---- MFMA self-calibration probes (wave 0; maps to LDS) ----
    if (wv == 0) {
        const int plm = lane & 15, plk = lane >> 4;
        v4d z = {0.0, 0.0, 0.0, 0.0};
        v4d p1 = __builtin_amdgcn_mfma_f64_16x16x4f64((double)plm, 1.0, z, 0, 0, 0);
        v4d p2 = __builtin_amdgcn_mfma_f64_16x16x4f64(1.0, (double)plm, z, 0, 0, 0);
        double pk = (double)(1 << plk);
        v4d p3 = __builtin_amdgcn_mfma_f64_16x16x4f64(pk, pk, z, 0, 0, 0);
        v4d p4 = __builtin_amdgcn_mfma_f64_16x16x4f64(1.0 + 0x1p-30, 1.0, z, 0, 0, 0);
        double pa5 = (plk == 0) ? 1.0 : 0x1p-52;
        v4d p5 = __builtin_amdgcn_mfma_f64_16x16x4f64(pa5, 1.0, z, 0, 0, 0);
        bool ok = true;
        #pragma unroll
        for (int i = 0; i < 4; ++i) {
            double v = p1[i]; int r = (int)(v * 0.25 + 0.5);
            ok = ok && (v == 4.0 * (double)r) && (r >= 0) && (r < 16);
            sPR[lane][i] = r;
            double w = p2[i]; int c2 = (int)(w * 0.25 + 0.5);
            ok = ok && (w == 4.0 * (double)c2) && (c2 >= 0) && (c2 < 16);
            sPC[lane][i] = c2;
            ok = ok && (p3[i] == 85.0);
            ok = ok && (p4[i] == 4.0 + 0x1p-28);
            ok = ok && (p5[i] == 1.0 + 3.0 * 0x1p-52);
        }
        unsigned long long bal = __ballot(ok ? 1 : 0);
        if (lane == 0) sFlag = (bal == 0xFFFFFFFFFFFFFFFFull) ? 1 : 0;
    }
    __syncthreads();
    const int useMfma = sFlag;

    const int rLN = tid >> 4;              // 0..63 : LN row (wave w -> rows 4w..4w+3)
    const int sL  = tid & 15;              // lane owns cols {sL + 16*j, j=0..7}
    const int lm  = lane & 15, lk = lane >> 4;
    const int rb  = (wv >> 3) * 32;        // row-pair base
    const int c0  = (wv & 7) * 16;         // MFMA col tile
    const int r0v = wv * 4;                // fallback rows (4/wave)
    const size_t rowg = (size_t)blockIdx.x * BR;

    #define STAGE_Q(LY, Q, QB)                                                      \
      { if (wp) {                                                                   \
          const double* src = wp + (((size_t)(LY) * D + (Q) * 32) * D);             \
          _Pragma("unroll")                                                         \
          for (int i_ = 0; i_ < 2; ++i_) {                                          \
              int kr_ = wv * 2 + i_;                                                \
              const double* g_ = src + (size_t)kr_ * D + lane * 2;                  \
              __builtin_amdgcn_global_load_lds(                                     \
                  (const __attribute__((address_space(1))) void*)g_,                \
                  (__attribute__((address_space(3))) void*)&sWq[QB][kr_][0],        \
                  16, 0, 0);                                                        \
          }                                                                         \
        } else {                                                                    \
          const float* src = Ws + (((size_t)(LY) * D + (Q) * 32) * D);              \
          const double* gl = &sGsD[LY][(Q) * 32];                                   \
          _Pragma("unroll")                                                         \
          for (int i_ = 0; i_ < 2; ++i_) {                                          \
              int kr_ = wv * 2 + i_;                                                \
              float2 w_ = *(const float2*)(src + (size_t)kr_ * D + lane * 2);       \
              double g_ = gl[kr_];                                                  \
              double2 o_; o_.x = g_ * (double)w_.x; o_.y = g_ * (double)w_.y;       \
              *(double2*)&sWq[QB][kr_][lane * 2] = o_;                              \
          }                                                                         \
        } }

    #define MFMA_Q(QB, QK)                                                          \
      { _Pragma("unroll")                                                           \
        for (int k0 = 0; k0 < 32; k0 += 4) {                                        \
            double b  = sWq[QB][k0 + lk][c0 + lm];                                  \
            double a0 = sState[rb + lm     ][(QK) + k0 + lk];                       \
            double a1 = sState[rb + lm + 16][(QK) + k0 + lk];                       \
            acc0 = __builtin_amdgcn_mfma_f64_16x16x4f64(a0, b, acc0, 0, 0, 0);      \
            acc1 = __builtin_amdgcn_mfma_f64_16x16x4f64(a1, b, acc1, 0, 0, 0);      \
        } }

    #define VALU_Q(QB, QK)                                                          \
      { _Pragma("unroll 4")                                                         \
        for (int kk = 0; kk < 32; kk += 2) {                                        \
            int kg = (QK) + kk;                                                     \
            double b00 = sWq[QB][kk][lane],     b01 = sWq[QB][kk][lane + 64];       \
            double b10 = sWq[QB][kk + 1][lane], b11 = sWq[QB][kk + 1][lane + 64];   \
            _Pragma("unroll")                                                       \
            for (int r = 0; r < 4; ++r) {                                           \
                double2 a = *(const double2*)&sState[r0v + r][kg];                  \
                accv[r][0] = fma(a.y, b10, fma(a.x, b00, accv[r][0]));              \
                accv[r][1] = fma(a.y, b11, fma(a.x, b01, accv[r][1]));              \
            }                                                                       \
        } }

    // streamed LN reduce -> sRstd/sMu2 (low-register: re-reads LDS)
    #define LN_BLOCK                                                                \
      { double sum = 0.0;                                                           \
        _Pragma("unroll")                                                           \
        for (int j = 0; j < 8; ++j) sum += sState[rLN][sL + 16 * j];                \
        sum += __shfl_xor(sum, 1); sum += __shfl_xor(sum, 2);                       \
        sum += __shfl_xor(sum, 4); sum += __shfl_xor(sum, 8);                       \
        double mu = sum * (1.0 / 128.0);                                            \
        double sq = 0.0;                                                            \
        _Pragma("unroll")                                                           \
        for (int j = 0; j < 8; ++j) { double dd = sState[rLN][sL + 16 * j] - mu; sq += dd * dd; } \
        sq += __shfl_xor(sq, 1); sq += __shfl_xor(sq, 2);                           \
        sq += __shfl_xor(sq, 4); sq += __shfl_xor(sq, 8);                           \
        double rstd = 1.0 / sqrt(sq * (1.0 / 128.0) + 1e-5);                        \
        if (sL == 0) { sRstd[rLN] = rstd; sMu2[rLN] = mu * rstd; } }

    STAGE_Q(0, 0, 0)   // prologue stage for t=0; drained at the post-step1 barrier

    for (int t = 0; t < TT; ++t) {
        // ---------- step 1 (wave-private rows, streamed / low-register) ----------
        {
            const float* xp = x + (rowg + (size_t)rLN) * (TT * NB) + (size_t)t * NB;
            float4 xa = *(const float4*)(xp);
            float4 xb = *(const float4*)(xp + 4);
            float xf[8] = {xa.x, xa.y, xa.z, xa.w, xb.x, xb.y, xb.z, xb.w};

            double sum = 0.0;
            #pragma unroll
            for (int j = 0; j < 8; ++j) sum += sState[rLN][sL + 16 * j];
            sum += __shfl_xor(sum, 1); sum += __shfl_xor(sum, 2);
            sum += __shfl_xor(sum, 4); sum += __shfl_xor(sum, 8);
            double mu = sum * (1.0 / 128.0);
            double sq = 0.0;
            #pragma unroll
            for (int j = 0; j < 8; ++j) { double dd = sState[rLN][sL + 16 * j] - mu; sq += dd * dd; }
            sq += __shfl_xor(sq, 1); sq += __shfl_xor(sq, 2);
            sq += __shfl_xor(sq, 4); sq += __shfl_xor(sq, 8);
            double rstd = 1.0 / sqrt(sq * (1.0 / 128.0) + 1e-5);

            #pragma unroll
            for (int j = 0; j < 8; ++j) {
                int c = sL + 16 * j;
                double v = sState[rLN][c];
                double inp = (double)sBi[c];
                #pragma unroll
                for (int k = 0; k < 8; ++k)
                    inp = fma((double)xf[k], (double)sWi[k][c], inp);
                double ln = (v - mu) * rstd * (double)sGst[c] + (double)sBst[c];
                sState[rLN][c] = 0.618 * ln + 0.382 * inp;
            }
        }
        __syncthreads();   // state ready; layer-0 q0 staged & drained

        // ---------- step 2: 3 residual layers (disjoint branches for liveness) ----------
        for (int ly = 0; ly < NL; ++ly) {
            if (useMfma) {
                v4d acc0 = {0,0,0,0}, acc1 = {0,0,0,0};
                STAGE_Q(ly, 1, 1)
                MFMA_Q(0, 0)
                LN_BLOCK
                __syncthreads();
                STAGE_Q(ly, 2, 0)  MFMA_Q(1, 32)  __syncthreads();
                STAGE_Q(ly, 3, 1)  MFMA_Q(0, 64)  __syncthreads();
                if (ly + 1 < NL) { STAGE_Q(ly + 1, 0, 0) } else { STAGE_Q(0, 0, 0) }
                MFMA_Q(1, 96)
                __syncthreads();
                // epilogue (probe maps from LDS, short-lived)
                #pragma unroll
                for (int i = 0; i < 4; ++i) {
                    int col = c0 + sPC[lane][i];
                    int R0  = rb + sPR[lane][i];
                    double gwc = sGW[ly][col], bwc = sBWbs[ly][col];
                    double y0 = fma(sRstd[R0],      acc0[i], fma(-sMu2[R0],      gwc, bwc));
                    double y1 = fma(sRstd[R0 + 16], acc1[i], fma(-sMu2[R0 + 16], gwc, bwc));
                    sState[R0][col]      += c19_act_d(y0);
                    sState[R0 + 16][col] += c19_act_d(y1);
                }
            } else {
                double accv[4][2];
                #pragma unroll
                for (int r = 0; r < 4; ++r) { accv[r][0] = 0.0; accv[r][1] = 0.0; }
                STAGE_Q(ly, 1, 1)
                VALU_Q(0, 0)
                LN_BLOCK
                __syncthreads();
                STAGE_Q(ly, 2, 0)  VALU_Q(1, 32)  __syncthreads();
                STAGE_Q(ly, 3, 1)  VALU_Q(0, 64)  __syncthreads();
                if (ly + 1 < NL) { STAGE_Q(ly + 1, 0, 0) } else { STAGE_Q(0, 0, 0) }
                VALU_Q(1, 96)
                __syncthreads();
                double gwc0 = sGW[ly][lane],   gwc1 = sGW[ly][lane + 64];
                double bwc0 = sBWbs[ly][lane], bwc1 = sBWbs[ly][lane + 64];
                #pragma unroll
                for (int r = 0; r < 4; ++r) {
                    int R = r0v + r;
                    double rs = sRstd[R], m2 = sMu2[R];
                    double y0 = fma(rs, accv[r][0], fma(-m2, gwc0, bwc0));
                    double y1 = fma(rs, accv[r][1], fma(-m2, gwc1, bwc1));
                    sState[R][lane]      += c19_act_d(y0);
                    sState[R][lane + 64] += c19_act_d(y1);
                }
            }
            __syncthreads();   // state final for next LN/GEMM/step3
        }

        // ---------- step 3: out = state @ Wo + bo (two 4-output passes, low-reg) ----------
        #pragma unroll
        for (int p = 0; p < 2; ++p) {
            double accj[4] = {0.0, 0.0, 0.0, 0.0};
            #pragma unroll
            for (int u = 0; u < 8; ++u) {
                int k = sL + 16 * u;
                double s = sState[rLN][k];
                float4 w = *(const float4*)&sWo[k][4 * p];
                accj[0] = fma(s, (double)w.x, accj[0]);
                accj[1] = fma(s, (double)w.y, accj[1]);
                accj[2] = fma(s, (double)w.z, accj[2]);
                accj[3] = fma(s, (double)w.w, accj[3]);
            }
            #pragma unroll
            for (int j = 0; j < 4; ++j) {
                accj[j] += __shfl_xor(accj[j], 1);
                accj[j] += __shfl_xor(accj[j], 2);
                accj[j] += __shfl_xor(accj[j], 4);
                accj[j] += __shfl_xor(accj[j], 8);
            }
            int jloc = sL - 4 * p;          // lane sL writes output sL (= 4p + jloc)
            double o = accj[0];
            #pragma unroll
            for (int j = 1; j < 4; ++j) o = (jloc == j) ? accj[j] : o;
            if (jloc >= 0 && jloc < 4)
                out[((rowg + (size_t)rLN) * TT + (size_t)t) * NB + sL] =
                    (float)(o + (double)sBo[sL]);
        }
    }
    #undef LN_BLOCK
    #undef VALU_Q
    #undef MFMA_Q
    #undef STAGE_Q
}

extern "C" void kernel_launch(void* const* d_in, const int* in_sizes, int n_in,
                              void* d_out, int out_size, void* d_ws, size_t ws_size,
                              hipStream_t stream) {
    const float* x       = (const float*)d_in[0];
    const float* Wi      = (const float*)d_in[1];
    const float* bi      = (const float*)d_in[2];
    const float* Wo      = (const float*)d_in[3];
    const float* bo      = (const float*)d_in[4];
    const float* g_state = (const float*)d_in[5];
    const float* b_state = (const float*)d_in[6];
    const float* Ws      = (const float*)d_in[7];
    const float* bs      = (const float*)d_in[8];
    const float* gs      = (const float*)d_in[9];
    const float* betas   = (const float*)d_in[10];
    float* out = (float*)d_out;

    const size_t wp_bytes = (size_t)NL * D * D * sizeof(double);   // 393216
    double* wp = (ws_size >= wp_bytes) ? (double*)d_ws : nullptr;
    if (wp) {
        dim3 pgrid(NL * D * D / 256), pblock(256);
        hipLaunchKernelGGL(miniphi_prep, pgrid, pblock, 0, stream, Ws, gs, wp);
    }

    const int B = in_sizes[0] / (TT * NB);   // 65536
    dim3 grid(B / BR), block(BDIM);
    hipLaunchKernelGGL(miniphi_kernel, grid, block, 0, stream,
                       x, Wi, bi, Wo, bo, g_state, b_state, Ws, bs, gs, betas, wp, out);
}